// Round 3
// baseline (474.552 us; speedup 1.0000x reference)
//
#include <hip/hip_runtime.h>
#include <hip/hip_bf16.h>
#include <math.h>

#define NUM_ENT 100000
#define DIM 768
#define BATCH 4096
#define INV_TAU 20.0f

typedef __attribute__((ext_vector_type(8))) short short8;   // 8 x bf16 (4 VGPRs)
typedef __attribute__((ext_vector_type(4))) float f32x4;    // MFMA accum

// ------------- Kernel 1: gather + L2-normalize, one wave per row ------------
__global__ __launch_bounds__(64) void gather_norm(
    const float* __restrict__ emb, const int* __restrict__ links,
    __hip_bfloat16* __restrict__ Z)
{
    int rowId = blockIdx.x;          // 0 .. 8191
    int b     = rowId >> 1;
    int which = rowId & 1;
    int src   = links[2 * b + which];
    const float4* srcRow = (const float4*)(emb + (size_t)src * DIM);

    int t = threadIdx.x;             // 0..63
    float4 v[3];
    float ss = 0.f;
    #pragma unroll
    for (int j = 0; j < 3; ++j) {    // 64 lanes x 3 float4 = 768 floats
        v[j] = srcRow[t + 64 * j];
        ss += v[j].x*v[j].x + v[j].y*v[j].y + v[j].z*v[j].z + v[j].w*v[j].w;
    }
    #pragma unroll
    for (int off = 32; off >= 1; off >>= 1) ss += __shfl_xor(ss, off);
    float scale = rsqrtf(ss);

    __hip_bfloat16* dst = Z + (size_t)(which * BATCH + b) * DIM;
    #pragma unroll
    for (int j = 0; j < 3; ++j) {
        union { ushort4 u; __hip_bfloat16 h[4]; } o;
        o.h[0] = __float2bfloat16(v[j].x * scale);
        o.h[1] = __float2bfloat16(v[j].y * scale);
        o.h[2] = __float2bfloat16(v[j].z * scale);
        o.h[3] = __float2bfloat16(v[j].w * scale);
        ((ushort4*)dst)[t + 64 * j] = o.u;
    }
}

// -------- Kernel 2: symmetric Z-gram, fused exp row+col sums ----------------
// Z = [h1; h2] (8192 x 768). G = Z Z^T is symmetric; upper triangle only.
//   aa = G[0:4096,0:4096], ab = G[0:4096,4096:], bb = G[4096:,4096:], ba=ab^T.
// Every upper element adds exp(logit) to S[gi] (row) and S[gj] (col).
// ab diagonal (gj-4096==gi) captured to diag[]; aa/bb diagonal masked; in
// diagonal-straddling blocks lower-triangle elements are zeroed.
// Block tile 128 rows x 256 cols, 4 waves (wave tile 64x128), double-buffered
// LDS with ONE barrier per K-chunk.
__global__ __launch_bounds__(256, 2) void gram_fused(
    const __hip_bfloat16* __restrict__ Z,
    float* __restrict__ S, float* __restrict__ diag)
{
    const int tj = blockIdx.x;               // col tile (256 wide), 0..31
    const int ti = blockIdx.y;               // row tile (128 tall), 0..63
    if (ti > 2 * tj + 1) return;             // below the diagonal: skip
    const bool straddle = ((ti >> 1) == tj); // block contains the diagonal

    __shared__ short sA[2][128 * 32];        // 2 x 8 KB
    __shared__ short sB[2][256 * 32];        // 2 x 16 KB

    const int t    = threadIdx.x;
    const int lane = t & 63;
    const int wave = t >> 6;
    const int wr   = wave >> 1, wc = wave & 1;   // 2x2 wave grid
    const int quad = lane >> 4, l16 = lane & 15;
    const int row0 = ti * 128;
    const int col0 = tj * 256;

    f32x4 acc[4][8];
    #pragma unroll
    for (int im = 0; im < 4; ++im)
        #pragma unroll
        for (int jn = 0; jn < 8; ++jn)
            acc[im][jn] = (f32x4){0.f, 0.f, 0.f, 0.f};

    // stage one 32-wide K-chunk of A(128 rows) and B(256 rows) into buffer bi.
    // K-slot position swizzled by (row>>1) for conflict-free ds_read_b128.
    auto issue = [&](int bi, int kk) {
        #pragma unroll
        for (int i = 0; i < 2; ++i) {        // sA: 512 chunks of 16 B
            int c = i * 256 + t, r = c >> 2, s = c & 3;
            int q8 = ((s - (r >> 1)) & 3) * 8;
            const __hip_bfloat16* g = Z + (size_t)(row0 + r) * DIM + kk + q8;
            __builtin_amdgcn_global_load_lds(
                (const __attribute__((address_space(1))) void*)g,
                (__attribute__((address_space(3))) void*)(&sA[bi][c * 8]), 16, 0, 0);
        }
        #pragma unroll
        for (int i = 0; i < 4; ++i) {        // sB: 1024 chunks of 16 B
            int c = i * 256 + t, r = c >> 2, s = c & 3;
            int q8 = ((s - (r >> 1)) & 3) * 8;
            const __hip_bfloat16* g = Z + (size_t)(col0 + r) * DIM + kk + q8;
            __builtin_amdgcn_global_load_lds(
                (const __attribute__((address_space(1))) void*)g,
                (__attribute__((address_space(3))) void*)(&sB[bi][c * 8]), 16, 0, 0);
        }
    };

    issue(0, 0);
    for (int it = 0; it < DIM / 32; ++it) {
        const int cur = it & 1;
        __syncthreads();                      // buf[cur] loads arrived; prior compute done
        if (it + 1 < DIM / 32) issue(cur ^ 1, (it + 1) * 32);

        short8 af[4], bf[8];
        #pragma unroll
        for (int im = 0; im < 4; ++im) {
            int row  = wr * 64 + im * 16 + l16;
            int slot = (quad + (row >> 1)) & 3;
            af[im] = *(const short8*)&sA[cur][row * 32 + slot * 8];
        }
        #pragma unroll
        for (int jn = 0; jn < 8; ++jn) {
            int row  = wc * 128 + jn * 16 + l16;
            int slot = (quad + (row >> 1)) & 3;
            bf[jn] = *(const short8*)&sB[cur][row * 32 + slot * 8];
        }
        #pragma unroll
        for (int im = 0; im < 4; ++im)
            #pragma unroll
            for (int jn = 0; jn < 8; ++jn)
                acc[im][jn] = __builtin_amdgcn_mfma_f32_16x16x32_bf16(
                    af[im], bf[jn], acc[im][jn], 0, 0, 0);
    }

    // epilogue: logits, exp, row sums + col sums, diag capture/masking
    float csum[8] = {0.f, 0.f, 0.f, 0.f, 0.f, 0.f, 0.f, 0.f};
    #pragma unroll
    for (int im = 0; im < 4; ++im) {
        #pragma unroll
        for (int r = 0; r < 4; ++r) {
            const int gi = row0 + wr * 64 + im * 16 + quad * 4 + r;
            float rsum = 0.f;
            #pragma unroll
            for (int jn = 0; jn < 8; ++jn) {
                const int gj = col0 + wc * 128 + jn * 16 + l16;
                float logit = acc[im][jn][r] * INV_TAU;
                if (gj - BATCH == gi) diag[gi] = logit;   // ab diagonal
                float e = __expf(logit);
                if (straddle && gi >= gj) e = 0.f;        // lower tri + aa/bb diag
                rsum += e;
                csum[jn] += e;
            }
            rsum += __shfl_xor(rsum, 1);
            rsum += __shfl_xor(rsum, 2);
            rsum += __shfl_xor(rsum, 4);
            rsum += __shfl_xor(rsum, 8);
            if (l16 == 0) atomicAdd(&S[gi], rsum);
        }
    }
    #pragma unroll
    for (int jn = 0; jn < 8; ++jn) {
        float c = csum[jn];
        c += __shfl_xor(c, 16);
        c += __shfl_xor(c, 32);
        if (quad == 0) {
            const int gj = col0 + wc * 128 + jn * 16 + l16;
            atomicAdd(&S[gj], c);
        }
    }
}

// ---------------- Kernel 3: finalize loss (single block) --------------------
__global__ __launch_bounds__(256) void finalize(
    const float* __restrict__ S, const float* __restrict__ diag,
    float* __restrict__ out)
{
    int t = threadIdx.x;
    float local = 0.f;
    for (int i = t; i < BATCH; i += 256) {
        float lse_a = logf(S[i]);
        float lse_b = logf(S[BATCH + i]);
        local += 0.5f * (lse_a + lse_b) - diag[i];
    }
    #pragma unroll
    for (int off = 32; off >= 1; off >>= 1) local += __shfl_xor(local, off);
    __shared__ float wsum[4];
    if ((t & 63) == 0) wsum[t >> 6] = local;
    __syncthreads();
    if (t == 0) out[0] = (wsum[0] + wsum[1] + wsum[2] + wsum[3]) / (float)BATCH;
}

extern "C" void kernel_launch(void* const* d_in, const int* in_sizes, int n_in,
                              void* d_out, int out_size, void* d_ws, size_t ws_size,
                              hipStream_t stream)
{
    const float* emb  = (const float*)d_in[0];
    const int* links  = (const int*)d_in[1];

    char* ws = (char*)d_ws;
    __hip_bfloat16* Z = (__hip_bfloat16*)ws;                         // 8192x768 bf16 = 12.6 MB
    float* S    = (float*)(ws + (size_t)2 * BATCH * DIM * 2);        // 8192 f32 (S_a | S_b)
    float* diag = (float*)(ws + (size_t)2 * BATCH * DIM * 2 + 2 * BATCH * 4); // 4096 f32

    hipMemsetAsync(S, 0, 2 * BATCH * sizeof(float), stream);

    gather_norm<<<dim3(2 * BATCH), 64, 0, stream>>>(emb, links, Z);
    gram_fused<<<dim3(32, 64), 256, 0, stream>>>(Z, S, diag);
    finalize<<<1, 256, 0, stream>>>(S, diag, (float*)d_out);
}

// Round 4
// 431.002 us; speedup vs baseline: 1.1010x; 1.1010x over previous
//
#include <hip/hip_runtime.h>
#include <hip/hip_bf16.h>
#include <math.h>

#define NUM_ENT 100000
#define DIM 768
#define BATCH 4096
#define INV_TAU 20.0f
#define QSCALE 16.0f                                   // pre-scale before fp8 quant
#define LOGIT_SCALE (INV_TAU / (QSCALE * QSCALE))      // undo QSCALE^2 after MFMA

typedef __attribute__((ext_vector_type(4))) float f32x4;    // MFMA accum

// ------- Kernel 1: gather + L2-normalize -> fp8 e4m3 (scaled by 16) ---------
__global__ __launch_bounds__(256) void gather_norm(
    const float* __restrict__ emb, const int* __restrict__ links,
    unsigned char* __restrict__ hn1, unsigned char* __restrict__ hn2)
{
    int rowId = blockIdx.x;          // 0 .. 2*BATCH-1
    int b     = rowId >> 1;
    int which = rowId & 1;
    int src   = links[2 * b + which];
    const float* srcRow = emb + (size_t)src * DIM;

    int t = threadIdx.x;
    float4 v = make_float4(0.f, 0.f, 0.f, 0.f);
    float ss = 0.f;
    if (t < DIM / 4) {               // 192 threads load float4 each
        v = ((const float4*)srcRow)[t];
        ss = v.x * v.x + v.y * v.y + v.z * v.z + v.w * v.w;
    }
    #pragma unroll
    for (int off = 32; off >= 1; off >>= 1) ss += __shfl_xor(ss, off);
    __shared__ float wsum[4];
    if ((t & 63) == 0) wsum[t >> 6] = ss;
    __syncthreads();
    float tot = wsum[0] + wsum[1] + wsum[2] + wsum[3];
    float scale = rsqrtf(tot) * QSCALE;

    if (t < DIM / 4) {
        unsigned char* dst = (which ? hn2 : hn1) + (size_t)b * DIM;
        int p = __builtin_amdgcn_cvt_pk_fp8_f32(v.x * scale, v.y * scale, 0, false);
        p     = __builtin_amdgcn_cvt_pk_fp8_f32(v.z * scale, v.w * scale, p, true);
        ((unsigned int*)dst)[t] = (unsigned int)p;
    }
}

// ------- Kernel 2: symmetric gram (fp8 MFMA) + exp row/col-sum --------------
// grid: (32 colTile, 32 rowTile, 3 matrices). block: 256 (4 waves).
// matId 0: ab = h1 x h2^T  full     : rowsum->S_a, colsum->S_b, diag capture
// matId 1: aa = h1 x h1^T  upper-tri: rowsum->S_a[gi]; off-diag also colsum->S_a[gj]
// matId 2: bb = h2 x h2^T  upper-tri: rowsum->S_b[gi]; off-diag also colsum->S_b[gj]
__global__ __launch_bounds__(256) void gram_sym(
    const unsigned char* __restrict__ hn1, const unsigned char* __restrict__ hn2,
    float* __restrict__ S, float* __restrict__ diag)
{
    const int ct = blockIdx.x;
    const int rt = blockIdx.y;
    const int matId = blockIdx.z;
    if (matId > 0 && ct < rt) return;   // symmetric matrices: upper triangle only

    const unsigned char* A  = (matId == 2) ? hn2 : hn1;
    const unsigned char* Bm = (matId == 1) ? hn1 : hn2;
    const int  rowTarget = (matId == 2) ? 1 : 0;
    const int  colTarget = (matId == 1) ? 0 : 1;
    const bool maskDiag  = (matId > 0) && (rt == ct);
    const bool doColsum  = (matId == 0) || (rt != ct);
    const bool captureDiag = (matId == 0);

    __shared__ unsigned char sA[128 * 32];   // 4 KB (fp8: 128 rows x 32 K-bytes)
    __shared__ unsigned char sB[128 * 32];   // 4 KB

    const int t    = threadIdx.x;
    const int lane = t & 63;
    const int wave = t >> 6;
    const int wm   = wave >> 1, wn = wave & 1;
    const int quad = lane >> 4, l16 = lane & 15;
    const int row0 = rt * 128;
    const int col0 = ct * 128;

    f32x4 acc[4][4];
    #pragma unroll
    for (int im = 0; im < 4; ++im)
        #pragma unroll
        for (int jn = 0; jn < 4; ++jn)
            acc[im][jn] = (f32x4){0.f, 0.f, 0.f, 0.f};

    for (int kk = 0; kk < DIM; kk += 32) {
        // stage 128x32B fp8 tiles, 16 B/lane direct global->LDS, 1 chunk/lane/tile.
        // 16-B half-row position rotated by (row>>2)&1 -> residual 2-way LDS
        // conflict on the b64 fragment reads (free per m136).
        {
            int r = t >> 1, h = t & 1;
            int koff = ((h + ((r >> 2) & 1)) & 1) * 16;
            const unsigned char* ga = A  + (size_t)(row0 + r) * DIM + kk + koff;
            const unsigned char* gb = Bm + (size_t)(col0 + r) * DIM + kk + koff;
            __builtin_amdgcn_global_load_lds(
                (const __attribute__((address_space(1))) void*)ga,
                (__attribute__((address_space(3))) void*)(sA + t * 16), 16, 0, 0);
            __builtin_amdgcn_global_load_lds(
                (const __attribute__((address_space(1))) void*)gb,
                (__attribute__((address_space(3))) void*)(sB + t * 16), 16, 0, 0);
        }
        __syncthreads();

        long long af[4], bfr[4];
        const int hk = quad >> 1, q8 = (quad & 1) * 8;
        #pragma unroll
        for (int im = 0; im < 4; ++im) {
            int row = wm * 64 + im * 16 + l16;
            int hl  = (hk + ((row >> 2) & 1)) & 1;
            af[im] = *(const long long*)&sA[row * 32 + hl * 16 + q8];
        }
        #pragma unroll
        for (int jn = 0; jn < 4; ++jn) {
            int row = wn * 64 + jn * 16 + l16;
            int hl  = (hk + ((row >> 2) & 1)) & 1;
            bfr[jn] = *(const long long*)&sB[row * 32 + hl * 16 + q8];
        }

        #pragma unroll
        for (int im = 0; im < 4; ++im)
            #pragma unroll
            for (int jn = 0; jn < 4; ++jn)
                acc[im][jn] = __builtin_amdgcn_mfma_f32_16x16x32_fp8_fp8(
                    af[im], bfr[jn], acc[im][jn], 0, 0, 0);
        __syncthreads();
    }

    // epilogue: logits, exp, row sums (+ col sums), diag capture/mask
    float csum[4] = {0.f, 0.f, 0.f, 0.f};
    #pragma unroll
    for (int im = 0; im < 4; ++im) {
        #pragma unroll
        for (int r = 0; r < 4; ++r) {
            const int gi = row0 + wm * 64 + im * 16 + quad * 4 + r;
            float rsum = 0.f;
            #pragma unroll
            for (int jn = 0; jn < 4; ++jn) {
                const int gj = col0 + wn * 64 + jn * 16 + l16;
                float logit = acc[im][jn][r] * LOGIT_SCALE;
                bool isDiag = (gi == gj);
                if (captureDiag && isDiag) diag[gi] = logit;
                float e = __expf(logit);
                if (maskDiag && isDiag) e = 0.f;
                rsum += e;
                csum[jn] += e;
            }
            rsum += __shfl_xor(rsum, 1);
            rsum += __shfl_xor(rsum, 2);
            rsum += __shfl_xor(rsum, 4);
            rsum += __shfl_xor(rsum, 8);
            if (l16 == 0) atomicAdd(&S[rowTarget * BATCH + gi], rsum);
        }
    }
    if (doColsum) {
        #pragma unroll
        for (int jn = 0; jn < 4; ++jn) {
            float c = csum[jn];
            c += __shfl_xor(c, 16);
            c += __shfl_xor(c, 32);
            if (quad == 0) {
                const int gj = col0 + wn * 64 + jn * 16 + l16;
                atomicAdd(&S[colTarget * BATCH + gj], c);
            }
        }
    }
}

// ---------------- Kernel 3: finalize loss (single block) --------------------
__global__ __launch_bounds__(256) void finalize(
    const float* __restrict__ S, const float* __restrict__ diag,
    float* __restrict__ out)
{
    int t = threadIdx.x;
    float local = 0.f;
    for (int i = t; i < BATCH; i += 256) {
        float lse_a = logf(S[i]);
        float lse_b = logf(S[BATCH + i]);
        local += 0.5f * (lse_a + lse_b) - diag[i];
    }
    #pragma unroll
    for (int off = 32; off >= 1; off >>= 1) local += __shfl_xor(local, off);
    __shared__ float wsum[4];
    if ((t & 63) == 0) wsum[t >> 6] = local;
    __syncthreads();
    if (t == 0) out[0] = (wsum[0] + wsum[1] + wsum[2] + wsum[3]) / (float)BATCH;
}

extern "C" void kernel_launch(void* const* d_in, const int* in_sizes, int n_in,
                              void* d_out, int out_size, void* d_ws, size_t ws_size,
                              hipStream_t stream)
{
    const float* emb  = (const float*)d_in[0];
    const int* links  = (const int*)d_in[1];

    char* ws = (char*)d_ws;
    unsigned char* hn1 = (unsigned char*)ws;                         // 3.1 MB fp8
    unsigned char* hn2 = (unsigned char*)(ws + (size_t)BATCH * DIM); // 3.1 MB fp8
    float* S    = (float*)(ws + (size_t)BATCH * DIM * 2);            // 2*4096 f32
    float* diag = (float*)(ws + (size_t)BATCH * DIM * 2 + 2 * BATCH * 4); // 4096 f32

    hipMemsetAsync(S, 0, 2 * BATCH * sizeof(float), stream);

    gather_norm<<<dim3(2 * BATCH), 256, 0, stream>>>(emb, links, hn1, hn2);
    gram_sym<<<dim3(32, 32, 3), 256, 0, stream>>>(hn1, hn2, S, diag);
    finalize<<<1, 256, 0, stream>>>(S, diag, (float*)d_out);
}